// Round 13
// baseline (186.660 us; speedup 1.0000x reference)
//
#include <hip/hip_runtime.h>
#include <hip/hip_fp16.h>

constexpr int N = 50000;        // nodes
constexpr int D = 64;           // feature dim
constexpr int E = 1600000;      // edges
constexpr int NBUCK = (N + 127) / 128;   // 391 buckets of 128 nodes (dst>>7)
constexpr int CAP = 4608;                // bucket window capacity (mean 4092)
constexpr int BTHREADS = 512;
constexpr int CPT = 8;                   // edges per thread in k_bucket
constexpr int EPB = BTHREADS * CPT;      // 4096 edges per block
constexpr int BUCK_BLOCKS = (E + EPB - 1) / EPB;  // 391

// ---------------------------------------------------------------------------
// K0: init per-bucket window cursors (cursor[b] = b*CAP)
__global__ void k_init(int* __restrict__ cursor) {
    int t = threadIdx.x;
    if (t < NBUCK) cursor[t] = t * CAP;
}

// K1: privatized counting-sort scatter -> fixed-capacity bucket windows.
// packed = dst<<16 | src (both < 65536); bucket = packed>>23.
// Edges are permuted into bucket-sorted order in LDS first, so global writes
// are contiguous runs (~21 edges) per bucket chunk instead of full scatter.
__global__ void k_bucket(const int* __restrict__ src, const int* __restrict__ dst,
                         int* __restrict__ cursor, unsigned* __restrict__ packed) {
    __shared__ int lh[NBUCK];
    __shared__ int scan[BTHREADS];
    __shared__ int lb[NBUCK];
    __shared__ unsigned stage[EPB];      // 16 KB
    int tid = threadIdx.x;
    for (int i = tid; i < NBUCK; i += BTHREADS) lh[i] = 0;
    __syncthreads();
    int base_e = blockIdx.x * EPB;
    unsigned pk[CPT];
    int bn[CPT], rk[CPT];
#pragma unroll
    for (int i = 0; i < CPT; ++i) {
        int e = base_e + i * BTHREADS + tid;
        if (e < E) {
            int d = dst[e];
            int s = src[e];
            bn[i] = d >> 7;
            pk[i] = ((unsigned)d << 16) | (unsigned)s;
            rk[i] = atomicAdd(&lh[bn[i]], 1);
        } else bn[i] = -1;
    }
    __syncthreads();
    // inclusive scan of lh over NBUCK (<=512)
    scan[tid] = (tid < NBUCK) ? lh[tid] : 0;
    __syncthreads();
    for (int off = 1; off < BTHREADS; off <<= 1) {
        int v = (tid >= off) ? scan[tid - off] : 0;
        __syncthreads();
        scan[tid] += v;
        __syncthreads();
    }
    if (tid < NBUCK) {
        int c = lh[tid];
        lb[tid] = c ? atomicAdd(&cursor[tid], c) : 0;  // one global atomic per bucket/block
    }
    __syncthreads();
#pragma unroll
    for (int i = 0; i < CPT; ++i) {
        if (bn[i] >= 0) {
            int eb = (bn[i] == 0) ? 0 : scan[bn[i] - 1];
            stage[eb + rk[i]] = pk[i];   // LDS scatter into bucket-sorted order
        }
    }
    __syncthreads();
    int tot = scan[NBUCK - 1];
    for (int j = tid; j < tot; j += BTHREADS) {
        unsigned v = stage[j];
        int bk = v >> 23;                // dst>>7
        int eb = (bk == 0) ? 0 : scan[bk - 1];
        packed[lb[bk] + (j - eb)] = v;   // contiguous within each chunk
    }
}

// K2: one block (512 thr) per 128-node bucket — LDS hist + scan -> rowptr/
// rowend/norm; fill node-sorted u16 src into LDS stage, then coalesced
// uint copy-out to the bucket's CSR window.
__global__ void k_csr(const int* __restrict__ cursor, const unsigned* __restrict__ packed,
                      unsigned short* __restrict__ csr, int* __restrict__ rowptr,
                      int* __restrict__ rowend, float* __restrict__ norm) {
    __shared__ int cnt[128];
    __shared__ int sm[128];
    __shared__ int cur[128];
    __shared__ unsigned short stage[CAP];   // 9 KB
    int b = blockIdx.x, tid = threadIdx.x;
    if (tid < 128) cnt[tid] = 0;
    __syncthreads();
    int beg = b * CAP;
    int m = cursor[b] - beg;                // edges in this bucket
    for (int j = tid; j < m; j += 512)
        atomicAdd(&cnt[(packed[beg + j] >> 16) & 127], 1);
    __syncthreads();
    if (tid < 128) sm[tid] = cnt[tid];
    __syncthreads();
    for (int off = 1; off < 128; off <<= 1) {
        int v = 0;
        if (tid < 128 && tid >= off) v = sm[tid - off];
        __syncthreads();
        if (tid < 128) sm[tid] += v;
        __syncthreads();
    }
    if (tid < 128) {
        int excl = (tid == 0) ? 0 : sm[tid - 1];
        int node = b * 128 + tid;
        if (node < N) {
            rowptr[node] = beg + excl;
            rowend[node] = beg + sm[tid];
            norm[node] = cnt[tid] ? rsqrtf((float)cnt[tid]) : 0.0f;
        }
        cur[tid] = excl;                    // local offset within stage
    }
    __syncthreads();
    for (int j = tid; j < m; j += 512) {
        unsigned p = packed[beg + j];
        int slot = atomicAdd(&cur[(p >> 16) & 127], 1);
        stage[slot] = (unsigned short)(p & 0xFFFFu);
    }
    __syncthreads();
    unsigned* du = (unsigned*)(csr + beg);  // beg even, base 4B-aligned
    const unsigned* su = (const unsigned*)stage;
    int mu = m >> 1;
    for (int k = tid; k < mu; k += 512) du[k] = su[k];
    if ((m & 1) && tid == 0) csr[beg + m - 1] = stage[m - 1];
}

// K3: h2 = (x@W)*norm, stored fp16 in SPLIT-PLANE layout:
// plane p = d>>5 holds features p*32..p*32+31; h2[p*N*32 + row*32 + (d&31)].
// Each 3.2 MB plane fits a 4 MiB per-XCD L2.
__global__ void k_gemm(const float* __restrict__ x, const float* __restrict__ W,
                       const float* __restrict__ norm, __half* __restrict__ h2) {
    __shared__ float Wl[64 * 64];
    __shared__ float xs[16][64];
    int tid = threadIdx.x;
    const float4* W4 = (const float4*)W;
    float4* Wl4 = (float4*)Wl;
    Wl4[tid] = W4[tid];
    int r = tid >> 6, d = tid & 63;
    int row = blockIdx.x * 16 + r;
    xs[r][d] = x[row * 64 + d];
    __syncthreads();
    float a = 0.0f;
#pragma unroll
    for (int k = 0; k < 64; ++k) a = fmaf(xs[r][k], Wl[k * 64 + d], a);
    h2[(size_t)(d >> 5) * (N * 32) + row * 32 + (d & 31)] = __float2half(a * norm[row]);
}

// K4: fused aggregate + dst-norm + bias + softplus, XCD-affine split planes.
// One wave per (node, plane). blockIdx%8 ~ XCD (dispatch heuristic): XCDs 0-3
// take plane 0, XCDs 4-7 plane 1, so each XCD gathers from a 3.2 MB working
// set that stays L2-resident. Lane = (edge-slot q=lane>>4, half2 fl=lane&15):
// one half2 load instruction covers 4 full 64B plane-rows. fp32 register
// accumulation; shfl_xor(16/32) reduce; 16-lane float2 epilogue.
__global__ void k_aggregate(const int* __restrict__ rowptr, const int* __restrict__ rowend,
                            const unsigned short* __restrict__ csr,
                            const __half* __restrict__ h2, const float* __restrict__ norm,
                            const float* __restrict__ bias, float* __restrict__ out) {
    int xcd = blockIdx.x & 7;
    int plane = xcd >> 2;                     // 0 or 1
    int o = (blockIdx.x >> 3) * 4 + (xcd & 3);  // [0, 12500)
    int node = o * 4 + (threadIdx.x >> 6);    // [0, 50000)
    int lane = threadIdx.x & 63;
    int q = lane >> 4;                        // edge slot 0..3
    int fl = lane & 15;                       // half2 chunk within 32-feature row
    const __half2* h2v = (const __half2*)(h2 + (size_t)plane * (N * 32));  // row=16 half2
    int beg = rowptr[node];
    int end = rowend[node];
    float ax = 0.0f, ay = 0.0f, bx = 0.0f, by = 0.0f;
    int j = beg;
    for (; j + 7 < end; j += 8) {             // 8 edges per wave iteration
        int s0 = csr[j + q];
        int s1 = csr[j + 4 + q];
        float2 v0 = __half22float2(h2v[s0 * 16 + fl]);
        float2 v1 = __half22float2(h2v[s1 * 16 + fl]);
        ax += v0.x;  ay += v0.y;
        bx += v1.x;  by += v1.y;
    }
    for (; j + 3 < end; j += 4) {             // 4-edge step
        int s = csr[j + q];
        float2 v = __half22float2(h2v[s * 16 + fl]);
        ax += v.x;  ay += v.y;
    }
    if (j < end) {                            // tail <4 edges, predicated
        bool act = (j + q) < end;
        int s = csr[act ? (j + q) : beg];
        float2 v = __half22float2(h2v[s * 16 + fl]);
        if (act) { ax += v.x;  ay += v.y; }
    }
    ax += bx;  ay += by;
    ax += __shfl_xor(ax, 16, 64);  ay += __shfl_xor(ay, 16, 64);
    ax += __shfl_xor(ax, 32, 64);  ay += __shfl_xor(ay, 32, 64);
    if (q == 0) {
        float nrm = norm[node];
        float2 bs = ((const float2*)bias)[plane * 16 + fl];
        float vx = ax * nrm + bs.x;
        float vy = ay * nrm + bs.y;
        float2 o2;
        o2.x = fmaxf(vx, 0.0f) + log1pf(expf(-fabsf(vx)));
        o2.y = fmaxf(vy, 0.0f) + log1pf(expf(-fabsf(vy)));
        ((float2*)out)[node * 32 + plane * 16 + fl] = o2;
    }
}

extern "C" void kernel_launch(void* const* d_in, const int* in_sizes, int n_in,
                              void* d_out, int out_size, void* d_ws, size_t ws_size,
                              hipStream_t stream) {
    // inputs: t(f32,1), x(f32,N*D), weight(f32,D*D), bias(f32,D), src(i32,E), dst(i32,E)
    const float* x    = (const float*)d_in[1];
    const float* W    = (const float*)d_in[2];
    const float* bias = (const float*)d_in[3];
    const int* src = (const int*)d_in[4];
    const int* dst = (const int*)d_in[5];
    float* out = (float*)d_out;

    // workspace layout (~17.9 MB; poisoned 0xAA every call — every buffer is
    // fully written before it is read)
    char* ws = (char*)d_ws;
    __half*         h2     = (__half*)(ws);                     // 6.4 MB (2 planes)
    unsigned*       packed = (unsigned*)(ws + 6400000);         // NBUCK*CAP*4 = 7.21 MB
    unsigned short* csr    = (unsigned short*)(ws + 13606912);  // NBUCK*CAP*2 = 3.6 MB
    int*            rowptr = (int*)(ws + 17210368);             // N*4
    int*            rowend = (int*)(ws + 17410368);             // N*4
    float*          norm   = (float*)(ws + 17610368);           // N*4
    int*            cursor = (int*)(ws + 17810368);             // NBUCK*4

    k_init     <<<1, 512, 0, stream>>>(cursor);
    k_bucket   <<<BUCK_BLOCKS, BTHREADS, 0, stream>>>(src, dst, cursor, packed);
    k_csr      <<<NBUCK, 512, 0, stream>>>(cursor, packed, csr, rowptr, rowend, norm);
    k_gemm     <<<(N + 15) / 16, 1024, 0, stream>>>(x, W, norm, h2);
    // grid = 25000 = 3125*8: each XCD (blockIdx%8) sticks to one h2 plane
    k_aggregate<<<25000, 256, 0, stream>>>(rowptr, rowend, csr, h2, norm, bias, out);
}

// Round 15
// 162.950 us; speedup vs baseline: 1.1455x; 1.1455x over previous
//
#include <hip/hip_runtime.h>
#include <hip/hip_fp16.h>

constexpr int N = 50000;        // nodes
constexpr int D = 64;           // feature dim
constexpr int E = 1600000;      // edges
constexpr int NBUCK = (N + 127) / 128;   // 391 buckets of 128 nodes (dst>>7)
constexpr int CAP = 4608;                // bucket window capacity (mean 4092)
constexpr int BTHREADS = 512;
constexpr int CPT = 8;                   // edges per thread in k_bucket
constexpr int EPB = BTHREADS * CPT;      // 4096 edges per block
constexpr int BUCK_BLOCKS = (E + EPB - 1) / EPB;  // 391

// ---------------------------------------------------------------------------
// K0: init per-bucket window cursors (cursor[b] = b*CAP)
__global__ void k_init(int* __restrict__ cursor) {
    int t = threadIdx.x;
    if (t < NBUCK) cursor[t] = t * CAP;
}

// K1: privatized counting-sort scatter -> fixed-capacity bucket windows.
// packed = dst<<16 | src (both < 65536); bucket = packed>>23.
// Edges are permuted into bucket-sorted order in LDS first, so global writes
// are contiguous runs (~21 edges) per bucket chunk instead of full scatter.
__global__ void k_bucket(const int* __restrict__ src, const int* __restrict__ dst,
                         int* __restrict__ cursor, unsigned* __restrict__ packed) {
    __shared__ int lh[NBUCK];
    __shared__ int scan[BTHREADS];
    __shared__ int lb[NBUCK];
    __shared__ unsigned stage[EPB];      // 16 KB
    int tid = threadIdx.x;
    for (int i = tid; i < NBUCK; i += BTHREADS) lh[i] = 0;
    __syncthreads();
    int base_e = blockIdx.x * EPB;
    unsigned pk[CPT];
    int bn[CPT], rk[CPT];
#pragma unroll
    for (int i = 0; i < CPT; ++i) {
        int e = base_e + i * BTHREADS + tid;
        if (e < E) {
            int d = dst[e];
            int s = src[e];
            bn[i] = d >> 7;
            pk[i] = ((unsigned)d << 16) | (unsigned)s;
            rk[i] = atomicAdd(&lh[bn[i]], 1);
        } else bn[i] = -1;
    }
    __syncthreads();
    // inclusive scan of lh over NBUCK (<=512)
    scan[tid] = (tid < NBUCK) ? lh[tid] : 0;
    __syncthreads();
    for (int off = 1; off < BTHREADS; off <<= 1) {
        int v = (tid >= off) ? scan[tid - off] : 0;
        __syncthreads();
        scan[tid] += v;
        __syncthreads();
    }
    if (tid < NBUCK) {
        int c = lh[tid];
        lb[tid] = c ? atomicAdd(&cursor[tid], c) : 0;  // one global atomic per bucket/block
    }
    __syncthreads();
#pragma unroll
    for (int i = 0; i < CPT; ++i) {
        if (bn[i] >= 0) {
            int eb = (bn[i] == 0) ? 0 : scan[bn[i] - 1];
            stage[eb + rk[i]] = pk[i];   // LDS scatter into bucket-sorted order
        }
    }
    __syncthreads();
    int tot = scan[NBUCK - 1];
    for (int j = tid; j < tot; j += BTHREADS) {
        unsigned v = stage[j];
        int bk = v >> 23;                // dst>>7
        int eb = (bk == 0) ? 0 : scan[bk - 1];
        packed[lb[bk] + (j - eb)] = v;   // contiguous within each chunk
    }
}

// K2: one block (512 thr) per 128-node bucket — LDS hist + scan -> rowptr/
// rowend/norm; fill node-sorted u16 src into LDS stage, then coalesced
// uint copy-out to the bucket's CSR window.
__global__ void k_csr(const int* __restrict__ cursor, const unsigned* __restrict__ packed,
                      unsigned short* __restrict__ csr, int* __restrict__ rowptr,
                      int* __restrict__ rowend, float* __restrict__ norm) {
    __shared__ int cnt[128];
    __shared__ int sm[128];
    __shared__ int cur[128];
    __shared__ unsigned short stage[CAP];   // 9 KB
    int b = blockIdx.x, tid = threadIdx.x;
    if (tid < 128) cnt[tid] = 0;
    __syncthreads();
    int beg = b * CAP;
    int m = cursor[b] - beg;                // edges in this bucket
    for (int j = tid; j < m; j += 512)
        atomicAdd(&cnt[(packed[beg + j] >> 16) & 127], 1);
    __syncthreads();
    if (tid < 128) sm[tid] = cnt[tid];
    __syncthreads();
    for (int off = 1; off < 128; off <<= 1) {
        int v = 0;
        if (tid < 128 && tid >= off) v = sm[tid - off];
        __syncthreads();
        if (tid < 128) sm[tid] += v;
        __syncthreads();
    }
    if (tid < 128) {
        int excl = (tid == 0) ? 0 : sm[tid - 1];
        int node = b * 128 + tid;
        if (node < N) {
            rowptr[node] = beg + excl;
            rowend[node] = beg + sm[tid];
            norm[node] = cnt[tid] ? rsqrtf((float)cnt[tid]) : 0.0f;
        }
        cur[tid] = excl;                    // local offset within stage
    }
    __syncthreads();
    for (int j = tid; j < m; j += 512) {
        unsigned p = packed[beg + j];
        int slot = atomicAdd(&cur[(p >> 16) & 127], 1);
        stage[slot] = (unsigned short)(p & 0xFFFFu);
    }
    __syncthreads();
    unsigned* du = (unsigned*)(csr + beg);  // beg even, base 4B-aligned
    const unsigned* su = (const unsigned*)stage;
    int mu = m >> 1;
    for (int k = tid; k < mu; k += 512) du[k] = su[k];
    if ((m & 1) && tid == 0) csr[beg + m - 1] = stage[m - 1];
}

// K3: h2[row][d] = (sum_k x[row][k] * W[k][d]) * norm[row], stored fp16
__global__ void k_gemm(const float* __restrict__ x, const float* __restrict__ W,
                       const float* __restrict__ norm, __half* __restrict__ h2) {
    __shared__ float Wl[64 * 64];
    __shared__ float xs[16][64];
    int tid = threadIdx.x;
    const float4* W4 = (const float4*)W;
    float4* Wl4 = (float4*)Wl;
    Wl4[tid] = W4[tid];
    int r = tid >> 6, d = tid & 63;
    int row = blockIdx.x * 16 + r;
    xs[r][d] = x[row * 64 + d];
    __syncthreads();
    float a = 0.0f;
#pragma unroll
    for (int k = 0; k < 64; ++k) a = fmaf(xs[r][k], Wl[k * 64 + d], a);
    h2[row * 64 + d] = __float2half(a * norm[row]);
}

// K4: fused aggregate + dst-norm + bias + softplus.
// One wave per node. Edge indices captured up-front (one u16 per lane covers
// deg<=64); the gather loop gets src via __shfl (no memory dependency), so
// gathers issue back-to-back limited only by vmcnt depth. ALL __shfl calls
// execute with the full wave active (wave-uniform conditions); divergent
// predicates only gate the accumulate. deg>64 falls back to direct loads.
__global__ void k_aggregate(const int* __restrict__ rowptr, const int* __restrict__ rowend,
                            const unsigned short* __restrict__ csr,
                            const __half* __restrict__ h2, const float* __restrict__ norm,
                            const float* __restrict__ bias, float* __restrict__ out) {
    int node = blockIdx.x * 4 + (threadIdx.x >> 6);
    int lane = threadIdx.x & 63;
    int half = lane >> 5;          // which edge of the pair
    int fl = lane & 31;            // feature-pair index (features 2fl, 2fl+1)
    const __half2* h2v = (const __half2*)h2;   // row stride 32
    int beg = rowptr[node];
    int end = rowend[node];
    int deg = end - beg;
    // up-front index capture: lane j holds csr[beg+j] (0 if OOB)
    int myidx = (beg + lane < end) ? (int)csr[beg + lane] : 0;
    int window = deg < 64 ? deg : 64;   // wave-uniform
    int npair = window >> 1;
    float ax = 0.0f, ay = 0.0f, bx = 0.0f, by = 0.0f;
    int p = 0;
    for (; p + 3 < npair; p += 4) {          // 8 edges per iteration, no index loads
        int s0 = __shfl(myidx, 2 * p + half, 64);
        int s1 = __shfl(myidx, 2 * p + 2 + half, 64);
        int s2 = __shfl(myidx, 2 * p + 4 + half, 64);
        int s3 = __shfl(myidx, 2 * p + 6 + half, 64);
        float2 v0 = __half22float2(h2v[s0 * 32 + fl]);
        float2 v1 = __half22float2(h2v[s1 * 32 + fl]);
        float2 v2 = __half22float2(h2v[s2 * 32 + fl]);
        float2 v3 = __half22float2(h2v[s3 * 32 + fl]);
        ax += v0.x + v2.x;  ay += v0.y + v2.y;
        bx += v1.x + v3.x;  by += v1.y + v3.y;
    }
    for (; p < npair; ++p) {                 // pair tail (uniform trip count)
        int s = __shfl(myidx, 2 * p + half, 64);
        float2 v = __half22float2(h2v[s * 32 + fl]);
        ax += v.x;  ay += v.y;
    }
    if (window & 1) {                        // wave-uniform: all lanes do the shfl
        int s = __shfl(myidx, window - 1, 64);
        float2 v = __half22float2(h2v[s * 32 + fl]);
        if (half == 0) { ax += v.x;  ay += v.y; }   // only the accumulate diverges
    }
    if (deg > 64) {                          // rare fallback, direct loads
        int j = beg + 64;
        for (; j + 1 < end; j += 2) {
            int s = csr[j + half];
            float2 v = __half22float2(h2v[s * 32 + fl]);
            ax += v.x;  ay += v.y;
        }
        if (j < end) {
            int s = csr[j];
            float2 v = __half22float2(h2v[s * 32 + fl]);
            if (half == 0) { ax += v.x;  ay += v.y; }
        }
    }
    ax += bx;  ay += by;
    ax += __shfl_xor(ax, 32, 64);            // combine the two half-waves
    ay += __shfl_xor(ay, 32, 64);
    if (half == 0) {
        float nrm = norm[node];
        float2 bs = ((const float2*)bias)[fl];
        float vx = ax * nrm + bs.x;
        float vy = ay * nrm + bs.y;
        float2 o;
        o.x = fmaxf(vx, 0.0f) + log1pf(expf(-fabsf(vx)));
        o.y = fmaxf(vy, 0.0f) + log1pf(expf(-fabsf(vy)));
        ((float2*)out)[node * 32 + fl] = o;
    }
}

extern "C" void kernel_launch(void* const* d_in, const int* in_sizes, int n_in,
                              void* d_out, int out_size, void* d_ws, size_t ws_size,
                              hipStream_t stream) {
    // inputs: t(f32,1), x(f32,N*D), weight(f32,D*D), bias(f32,D), src(i32,E), dst(i32,E)
    const float* x    = (const float*)d_in[1];
    const float* W    = (const float*)d_in[2];
    const float* bias = (const float*)d_in[3];
    const int* src = (const int*)d_in[4];
    const int* dst = (const int*)d_in[5];
    float* out = (float*)d_out;

    // workspace layout (~17.9 MB; poisoned 0xAA every call — every buffer is
    // fully written before it is read)
    char* ws = (char*)d_ws;
    __half*         h2     = (__half*)(ws);                     // 6.4 MB
    unsigned*       packed = (unsigned*)(ws + 6400000);         // NBUCK*CAP*4 = 7.21 MB
    unsigned short* csr    = (unsigned short*)(ws + 13606912);  // NBUCK*CAP*2 = 3.6 MB
    int*            rowptr = (int*)(ws + 17210368);             // N*4
    int*            rowend = (int*)(ws + 17410368);             // N*4
    float*          norm   = (float*)(ws + 17610368);           // N*4
    int*            cursor = (int*)(ws + 17810368);             // NBUCK*4

    k_init     <<<1, 512, 0, stream>>>(cursor);
    k_bucket   <<<BUCK_BLOCKS, BTHREADS, 0, stream>>>(src, dst, cursor, packed);
    k_csr      <<<NBUCK, 512, 0, stream>>>(cursor, packed, csr, rowptr, rowend, norm);
    k_gemm     <<<(N + 15) / 16, 1024, 0, stream>>>(x, W, norm, h2);
    k_aggregate<<<(N + 3) / 4, 256, 0, stream>>>(rowptr, rowend, csr, h2, norm, bias, out);
}

// Round 16
// 161.555 us; speedup vs baseline: 1.1554x; 1.0086x over previous
//
#include <hip/hip_runtime.h>
#include <hip/hip_fp16.h>

constexpr int N = 50000;        // nodes
constexpr int D = 64;           // feature dim
constexpr int E = 1600000;      // edges
constexpr int NBUCK = (N + 127) / 128;   // 391 buckets of 128 nodes (dst>>7)
constexpr int CAP = 4608;                // bucket window capacity (mean 4092)
constexpr int BTHREADS = 512;
constexpr int BBLOCKS = 512;             // 2 blocks/CU exactly
constexpr int EPB = E / BBLOCKS;         // 3125 edges per block (exact)
constexpr int CPT = (EPB + BTHREADS - 1) / BTHREADS;  // 7

// ---------------------------------------------------------------------------
// K0: init per-bucket window cursors (cursor[b] = b*CAP)
__global__ void k_init(int* __restrict__ cursor) {
    int t = threadIdx.x;
    if (t < NBUCK) cursor[t] = t * CAP;
}

// K1: privatized counting-sort scatter -> fixed-capacity bucket windows.
// packed = dst<<16 | src (both < 65536); bucket = packed>>23.
// Edges permuted into bucket-sorted order in LDS first (contiguous chunk
// writes). Scan = hierarchical wave shfl (3 barriers, not 18). Grid = 512
// blocks = exactly 2/CU for balance.
__global__ void k_bucket(const int* __restrict__ src, const int* __restrict__ dst,
                         int* __restrict__ cursor, unsigned* __restrict__ packed) {
    __shared__ int lh[NBUCK];
    __shared__ int scanI[NBUCK];         // inclusive prefix over buckets
    __shared__ int wsum[8];
    __shared__ int lb[NBUCK];
    __shared__ unsigned stage[EPB];      // 12.5 KB
    int tid = threadIdx.x;
    if (tid < NBUCK) lh[tid] = 0;
    __syncthreads();
    int base_e = blockIdx.x * EPB;
    unsigned pk[CPT];
    int bn[CPT], rk[CPT];
#pragma unroll
    for (int i = 0; i < CPT; ++i) {
        int idx = i * BTHREADS + tid;
        if (idx < EPB) {
            int e = base_e + idx;
            int d = dst[e];
            int s = src[e];
            bn[i] = d >> 7;
            pk[i] = ((unsigned)d << 16) | (unsigned)s;
            rk[i] = atomicAdd(&lh[bn[i]], 1);
        } else bn[i] = -1;
    }
    __syncthreads();
    // hierarchical inclusive scan of lh[0..NBUCK) into scanI
    int w = tid >> 6, l = tid & 63;
    int v = (tid < NBUCK) ? lh[tid] : 0;
    for (int off = 1; off < 64; off <<= 1) {
        int t = __shfl_up(v, off, 64);
        if (l >= off) v += t;
    }
    if (tid < NBUCK) scanI[tid] = v;
    if (l == 63) wsum[w] = v;
    __syncthreads();
    if (tid < 64) {                      // wave 0 scans the 8 wave sums
        int s = (tid < 8) ? wsum[tid] : 0;
        for (int off = 1; off < 8; off <<= 1) {
            int t = __shfl_up(s, off, 64);
            if (tid >= off) s += t;
        }
        if (tid < 8) wsum[tid] = s;
    }
    __syncthreads();
    if (tid < NBUCK && w > 0) scanI[tid] += wsum[w - 1];
    if (tid < NBUCK) {
        int c = lh[tid];
        lb[tid] = c ? atomicAdd(&cursor[tid], c) : 0;   // one global atomic/bucket/block
    }
    __syncthreads();
#pragma unroll
    for (int i = 0; i < CPT; ++i) {
        if (bn[i] >= 0) {
            int eb = (bn[i] == 0) ? 0 : scanI[bn[i] - 1];
            stage[eb + rk[i]] = pk[i];   // LDS scatter into bucket-sorted order
        }
    }
    __syncthreads();
    for (int j = tid; j < EPB; j += BTHREADS) {
        unsigned vv = stage[j];
        int bk = vv >> 23;               // dst>>7
        int eb = (bk == 0) ? 0 : scanI[bk - 1];
        packed[lb[bk] + (j - eb)] = vv;  // contiguous within each chunk
    }
}

// K2: one block (1024 thr) per 128-node bucket — LDS hist + single-wave shfl
// scan -> rowptr/rowend/norm; fill node-sorted u16 src into LDS stage, then
// coalesced uint copy-out to the bucket's CSR window.
__global__ void k_csr(const int* __restrict__ cursor, const unsigned* __restrict__ packed,
                      unsigned short* __restrict__ csr, int* __restrict__ rowptr,
                      int* __restrict__ rowend, float* __restrict__ norm) {
    __shared__ int cnt[128];
    __shared__ int sm[128];              // inclusive prefix over 128 bins
    __shared__ int cur[128];
    __shared__ unsigned short stage[CAP];   // 9 KB
    int b = blockIdx.x, tid = threadIdx.x;
    if (tid < 128) cnt[tid] = 0;
    __syncthreads();
    int beg = b * CAP;
    int m = cursor[b] - beg;                // edges in this bucket
    for (int j = tid; j < m; j += 1024)
        atomicAdd(&cnt[(packed[beg + j] >> 16) & 127], 1);
    __syncthreads();
    if (tid < 64) {                      // wave 0: 2 bins/lane inclusive scan
        int a = cnt[2 * tid], c1 = cnt[2 * tid + 1];
        int s = a + c1;
        for (int off = 1; off < 64; off <<= 1) {
            int t = __shfl_up(s, off, 64);
            if (tid >= off) s += t;
        }
        sm[2 * tid + 1] = s;             // incl(2t+1)
        sm[2 * tid] = s - c1;            // incl(2t)
    }
    __syncthreads();
    if (tid < 128) {
        int incl = sm[tid];
        int excl = incl - cnt[tid];
        int node = b * 128 + tid;
        if (node < N) {
            rowptr[node] = beg + excl;
            rowend[node] = beg + incl;
            norm[node] = cnt[tid] ? rsqrtf((float)cnt[tid]) : 0.0f;
        }
        cur[tid] = excl;                 // local offset within stage
    }
    __syncthreads();
    for (int j = tid; j < m; j += 1024) {
        unsigned p = packed[beg + j];
        int slot = atomicAdd(&cur[(p >> 16) & 127], 1);
        stage[slot] = (unsigned short)(p & 0xFFFFu);
    }
    __syncthreads();
    unsigned* du = (unsigned*)(csr + beg);  // beg even, base 4B-aligned
    const unsigned* su = (const unsigned*)stage;
    int mu = m >> 1;
    for (int k = tid; k < mu; k += 1024) du[k] = su[k];
    if ((m & 1) && tid == 0) csr[beg + m - 1] = stage[m - 1];
}

// K3: h2[row][d] = (sum_k x[row][k] * W[k][d]) * norm[row], stored fp16
__global__ void k_gemm(const float* __restrict__ x, const float* __restrict__ W,
                       const float* __restrict__ norm, __half* __restrict__ h2) {
    __shared__ float Wl[64 * 64];
    __shared__ float xs[16][64];
    int tid = threadIdx.x;
    const float4* W4 = (const float4*)W;
    float4* Wl4 = (float4*)Wl;
    Wl4[tid] = W4[tid];
    int r = tid >> 6, d = tid & 63;
    int row = blockIdx.x * 16 + r;
    xs[r][d] = x[row * 64 + d];
    __syncthreads();
    float a = 0.0f;
#pragma unroll
    for (int k = 0; k < 64; ++k) a = fmaf(xs[r][k], Wl[k * 64 + d], a);
    h2[row * 64 + d] = __float2half(a * norm[row]);
}

// K4: fused aggregate + dst-norm + bias + softplus (R15, known-good).
// One wave per node; edge indices captured up-front (u16/lane, deg<=64);
// gather loop gets src via __shfl — no memory dependency on the index leg.
// All __shfl calls run with the full wave active; only accumulates diverge.
__global__ void k_aggregate(const int* __restrict__ rowptr, const int* __restrict__ rowend,
                            const unsigned short* __restrict__ csr,
                            const __half* __restrict__ h2, const float* __restrict__ norm,
                            const float* __restrict__ bias, float* __restrict__ out) {
    int node = blockIdx.x * 4 + (threadIdx.x >> 6);
    int lane = threadIdx.x & 63;
    int half = lane >> 5;          // which edge of the pair
    int fl = lane & 31;            // feature-pair index (features 2fl, 2fl+1)
    const __half2* h2v = (const __half2*)h2;   // row stride 32
    int beg = rowptr[node];
    int end = rowend[node];
    int deg = end - beg;
    int myidx = (beg + lane < end) ? (int)csr[beg + lane] : 0;
    int window = deg < 64 ? deg : 64;   // wave-uniform
    int npair = window >> 1;
    float ax = 0.0f, ay = 0.0f, bx = 0.0f, by = 0.0f;
    int p = 0;
    for (; p + 3 < npair; p += 4) {          // 8 edges per iteration, no index loads
        int s0 = __shfl(myidx, 2 * p + half, 64);
        int s1 = __shfl(myidx, 2 * p + 2 + half, 64);
        int s2 = __shfl(myidx, 2 * p + 4 + half, 64);
        int s3 = __shfl(myidx, 2 * p + 6 + half, 64);
        float2 v0 = __half22float2(h2v[s0 * 32 + fl]);
        float2 v1 = __half22float2(h2v[s1 * 32 + fl]);
        float2 v2 = __half22float2(h2v[s2 * 32 + fl]);
        float2 v3 = __half22float2(h2v[s3 * 32 + fl]);
        ax += v0.x + v2.x;  ay += v0.y + v2.y;
        bx += v1.x + v3.x;  by += v1.y + v3.y;
    }
    for (; p < npair; ++p) {                 // pair tail (uniform trip count)
        int s = __shfl(myidx, 2 * p + half, 64);
        float2 v = __half22float2(h2v[s * 32 + fl]);
        ax += v.x;  ay += v.y;
    }
    if (window & 1) {                        // wave-uniform: all lanes shfl
        int s = __shfl(myidx, window - 1, 64);
        float2 v = __half22float2(h2v[s * 32 + fl]);
        if (half == 0) { ax += v.x;  ay += v.y; }
    }
    if (deg > 64) {                          // rare fallback, direct loads
        int j = beg + 64;
        for (; j + 1 < end; j += 2) {
            int s = csr[j + half];
            float2 v = __half22float2(h2v[s * 32 + fl]);
            ax += v.x;  ay += v.y;
        }
        if (j < end) {
            int s = csr[j];
            float2 v = __half22float2(h2v[s * 32 + fl]);
            if (half == 0) { ax += v.x;  ay += v.y; }
        }
    }
    ax += bx;  ay += by;
    ax += __shfl_xor(ax, 32, 64);            // combine the two half-waves
    ay += __shfl_xor(ay, 32, 64);
    if (half == 0) {
        float nrm = norm[node];
        float2 bs = ((const float2*)bias)[fl];
        float vx = ax * nrm + bs.x;
        float vy = ay * nrm + bs.y;
        float2 o;
        o.x = fmaxf(vx, 0.0f) + log1pf(expf(-fabsf(vx)));
        o.y = fmaxf(vy, 0.0f) + log1pf(expf(-fabsf(vy)));
        ((float2*)out)[node * 32 + fl] = o;
    }
}

extern "C" void kernel_launch(void* const* d_in, const int* in_sizes, int n_in,
                              void* d_out, int out_size, void* d_ws, size_t ws_size,
                              hipStream_t stream) {
    // inputs: t(f32,1), x(f32,N*D), weight(f32,D*D), bias(f32,D), src(i32,E), dst(i32,E)
    const float* x    = (const float*)d_in[1];
    const float* W    = (const float*)d_in[2];
    const float* bias = (const float*)d_in[3];
    const int* src = (const int*)d_in[4];
    const int* dst = (const int*)d_in[5];
    float* out = (float*)d_out;

    // workspace layout (~17.9 MB; poisoned 0xAA every call — every buffer is
    // fully written before it is read)
    char* ws = (char*)d_ws;
    __half*         h2     = (__half*)(ws);                     // 6.4 MB
    unsigned*       packed = (unsigned*)(ws + 6400000);         // NBUCK*CAP*4 = 7.21 MB
    unsigned short* csr    = (unsigned short*)(ws + 13606912);  // NBUCK*CAP*2 = 3.6 MB
    int*            rowptr = (int*)(ws + 17210368);             // N*4
    int*            rowend = (int*)(ws + 17410368);             // N*4
    float*          norm   = (float*)(ws + 17610368);           // N*4
    int*            cursor = (int*)(ws + 17810368);             // NBUCK*4

    k_init     <<<1, 512, 0, stream>>>(cursor);
    k_bucket   <<<BBLOCKS, BTHREADS, 0, stream>>>(src, dst, cursor, packed);
    k_csr      <<<NBUCK, 1024, 0, stream>>>(cursor, packed, csr, rowptr, rowend, norm);
    k_gemm     <<<(N + 15) / 16, 1024, 0, stream>>>(x, W, norm, h2);
    k_aggregate<<<(N + 3) / 4, 256, 0, stream>>>(rowptr, rowend, csr, h2, norm, bias, out);
}